// Round 14
// baseline (84.182 us; speedup 1.0000x reference)
//
#include <hip/hip_runtime.h>
#include <math.h>

#define B_DIM 256
#define M_DIM 256
#define C_DIM 1024
#define C4    256            // C/4 float4 per row
#define UM_OFF (B_DIM * C_DIM)                       // 262144 floats
#define KL_OFF (UM_OFF + B_DIM * M_DIM * C_DIM)      // 67371008 floats
#define SCALE  0.03125f      // 1/sqrt(1024)
#define NPRE   64            // prefix blocks (4 batches each)
#define NSTRM  2048          // stream blocks (8 rows x 4 batches each)

__device__ __forceinline__ float dot4(float4 a, float4 b) {
    return a.x*b.x + a.y*b.y + a.z*b.z + a.w*b.w;
}
__device__ __forceinline__ float wsum(float v) {
    #pragma unroll
    for (int off = 32; off; off >>= 1) v += __shfl_xor(v, off, 64);
    return v;
}
__device__ __forceinline__ float wmax(float v) {
    #pragma unroll
    for (int off = 32; off; off >>= 1) v = fmaxf(v, __shfl_xor(v, off, 64));
    return v;
}
__device__ __forceinline__ float4 blend9(float4 v, float4 xr) {
    return make_float4(0.9f*v.x + 0.1f*xr.x, 0.9f*v.y + 0.1f*xr.y,
                       0.9f*v.z + 0.1f*xr.z, 0.9f*v.w + 0.1f*xr.w);
}

// Kernel A: 64 prefix blocks (bid<64) + 2048 stream blocks. 256 thr.
__global__ __launch_bounds__(256) void tm_main(const float* __restrict__ x,
                                               const float* __restrict__ mem,
                                               float* __restrict__ out,
                                               int* __restrict__ idx_ws) {
    const int bid = blockIdx.x;
    const int t = threadIdx.x;
    const float4* mem4 = (const float4*)mem;

    if (bid >= NPRE) {
        // ============ stream role: read 8 rows once, write to 4 batches ====
        const int j  = bid - NPRE;       // 0..2047
        const int b0 = (j >> 5) << 2;    // 0,4,...,252
        const int m0 = (j & 31) << 3;    // 0,8,...,248
        const float4* src = mem4 + (m0 << 8) + t;
        float4 r0 = src[0 << 8];
        float4 r1 = src[1 << 8];
        float4 r2 = src[2 << 8];
        float4 r3 = src[3 << 8];
        float4 r4 = src[4 << 8];
        float4 r5 = src[5 << 8];
        float4 r6 = src[6 << 8];
        float4 r7 = src[7 << 8];
        float4* dstb = (float4*)(out + UM_OFF);
        #pragma unroll
        for (int jb = 0; jb < 4; ++jb) {
            float4* dst = dstb + ((size_t)(b0 + jb) << 16) + (m0 << 8) + t;
            dst[0 << 8] = r0;
            dst[1 << 8] = r1;
            dst[2 << 8] = r2;
            dst[3 << 8] = r3;
            dst[4 << 8] = r4;
            dst[5 << 8] = r5;
            dst[6 << 8] = r6;
            dst[7 << 8] = r7;
        }
        return;
    }

    // ============ prefix role: 4 batches b0..b0+3 =========================
    const int lane = t & 63;
    const int wv = t >> 6;     // 0..3
    const int b0 = bid << 2;

    __shared__ float4 s_x[4][C4];        // 16 KB
    __shared__ float  s_sims[4][M_DIM];  // 4 KB
    __shared__ float  s_attnT[M_DIM*4];  // 4 KB  [m][j]
    __shared__ float  s_aidx[4];
    __shared__ float  s_dw[4];
    __shared__ int    s_idxv[4];
    __shared__ float4 s_red4[4];

    #pragma unroll
    for (int j = 0; j < 4; ++j)
        s_x[j][t] = ((const float4*)(x + (size_t)(b0 + j) * C_DIM))[t];
    __syncthreads();                                   // barrier 1

    // ---- sims: wave wv owns m in [wv*64, +64); one mem pass for 4 batches ----
    {
        const float4 x00 = s_x[0][lane], x01 = s_x[0][lane+64], x02 = s_x[0][lane+128], x03 = s_x[0][lane+192];
        const float4 x10 = s_x[1][lane], x11 = s_x[1][lane+64], x12 = s_x[1][lane+128], x13 = s_x[1][lane+192];
        const float4 x20 = s_x[2][lane], x21 = s_x[2][lane+64], x22 = s_x[2][lane+128], x23 = s_x[2][lane+192];
        const float4 x30 = s_x[3][lane], x31 = s_x[3][lane+64], x32 = s_x[3][lane+128], x33 = s_x[3][lane+192];
        #pragma unroll 2
        for (int i = 0; i < 64; ++i) {
            const int m = (wv << 6) | i;
            const float4* mr = mem4 + (m << 8);
            float4 a0 = mr[lane];
            float4 a1 = mr[lane + 64];
            float4 a2 = mr[lane + 128];
            float4 a3 = mr[lane + 192];
            float p0 = dot4(a0,x00) + dot4(a1,x01) + dot4(a2,x02) + dot4(a3,x03);
            float p1 = dot4(a0,x10) + dot4(a1,x11) + dot4(a2,x12) + dot4(a3,x13);
            float p2 = dot4(a0,x20) + dot4(a1,x21) + dot4(a2,x22) + dot4(a3,x23);
            float p3 = dot4(a0,x30) + dot4(a1,x31) + dot4(a2,x32) + dot4(a3,x33);
            #pragma unroll
            for (int off = 32; off; off >>= 1) {
                p0 += __shfl_xor(p0, off, 64);
                p1 += __shfl_xor(p1, off, 64);
                p2 += __shfl_xor(p2, off, 64);
                p3 += __shfl_xor(p3, off, 64);
            }
            if (lane == 0) {
                s_sims[0][m] = p0; s_sims[1][m] = p1;
                s_sims[2][m] = p2; s_sims[3][m] = p3;
            }
        }
    }
    __syncthreads();                                   // barrier 2

    // ---- softmax: wave wv owns batch j = wv entirely (no cross-wave sync) ----
    {
        const int j = wv;
        const float v0 = s_sims[j][lane];
        const float v1 = s_sims[j][lane + 64];
        const float v2 = s_sims[j][lane + 128];
        const float v3 = s_sims[j][lane + 192];
        const float4 xa = s_x[j][lane], xb = s_x[j][lane + 64];
        const float4 xc = s_x[j][lane + 128], xd = s_x[j][lane + 192];
        const float n2 = wsum(dot4(xa,xa) + dot4(xb,xb) + dot4(xc,xc) + dot4(xd,xd));

        float av = v0; int am = lane;
        if (v1 > av) { av = v1; am = lane + 64; }
        if (v2 > av) { av = v2; am = lane + 128; }
        if (v3 > av) { av = v3; am = lane + 192; }
        #pragma unroll
        for (int off = 32; off; off >>= 1) {
            float ov = __shfl_xor(av, off, 64);
            int   oi = __shfl_xor(am, off, 64);
            if (ov > av || (ov == av && oi < am)) { av = ov; am = oi; }
        }
        const int idx = am;
        const float fused = 0.9f * av + 0.1f * n2;

        float s0 = ((lane      ) == idx ? fused : v0) * SCALE;
        float s1 = ((lane +  64) == idx ? fused : v1) * SCALE;
        float s2 = ((lane + 128) == idx ? fused : v2) * SCALE;
        float s3 = ((lane + 192) == idx ? fused : v3) * SCALE;
        const float mx = wmax(fmaxf(fmaxf(s0, s1), fmaxf(s2, s3)));
        const float e0 = expf(s0 - mx), e1 = expf(s1 - mx);
        const float e2 = expf(s2 - mx), e3 = expf(s3 - mx);
        const float inv = 1.0f / wsum(e0 + e1 + e2 + e3);
        const float a0 = e0 * inv, a1 = e1 * inv, a2 = e2 * inv, a3 = e3 * inv;

        s_attnT[(lane      ) * 4 + j] = a0;
        s_attnT[(lane +  64) * 4 + j] = a1;
        s_attnT[(lane + 128) * 4 + j] = a2;
        s_attnT[(lane + 192) * 4 + j] = a3;

        float aidx;
        if      (idx <  64) aidx = __shfl(a0, idx,       64);
        else if (idx < 128) aidx = __shfl(a1, idx - 64,  64);
        else if (idx < 192) aidx = __shfl(a2, idx - 128, 64);
        else                aidx = __shfl(a3, idx - 192, 64);

        // dw = ||x - mem[idx]||^2
        const float4* ir = mem4 + (idx << 8);
        float4 q0 = ir[lane], q1 = ir[lane+64], q2 = ir[lane+128], q3 = ir[lane+192];
        float p = 0.f; float4 dq;
        dq = make_float4(xa.x-q0.x, xa.y-q0.y, xa.z-q0.z, xa.w-q0.w); p += dot4(dq,dq);
        dq = make_float4(xb.x-q1.x, xb.y-q1.y, xb.z-q1.z, xb.w-q1.w); p += dot4(dq,dq);
        dq = make_float4(xc.x-q2.x, xc.y-q2.y, xc.z-q2.z, xc.w-q2.w); p += dot4(dq,dq);
        dq = make_float4(xd.x-q3.x, xd.y-q3.y, xd.z-q3.z, xd.w-q3.w); p += dot4(dq,dq);
        const float dwv = wsum(p);

        if (lane == 0) {
            s_idxv[j] = idx;
            s_aidx[j] = aidx * 0.1f;
            s_dw[j]   = dwv;
            idx_ws[b0 + j] = idx;       // consumed by tm_fix next dispatch
        }
    }
    __syncthreads();                                   // barrier 3

    // ---- z pass: one mem pass serves 4 batches; thread t owns column t ----
    float4 z0 = make_float4(0,0,0,0), z1 = z0, z2 = z0, z3 = z0;
    const float4* attn4 = (const float4*)s_attnT;
    #pragma unroll 8
    for (int m = 0; m < M_DIM; ++m) {
        float4 v = mem4[(m << 8) + t];
        float4 a = attn4[m];
        z0.x = fmaf(a.x, v.x, z0.x); z0.y = fmaf(a.x, v.y, z0.y);
        z0.z = fmaf(a.x, v.z, z0.z); z0.w = fmaf(a.x, v.w, z0.w);
        z1.x = fmaf(a.y, v.x, z1.x); z1.y = fmaf(a.y, v.y, z1.y);
        z1.z = fmaf(a.y, v.z, z1.z); z1.w = fmaf(a.y, v.w, z1.w);
        z2.x = fmaf(a.z, v.x, z2.x); z2.y = fmaf(a.z, v.y, z2.y);
        z2.z = fmaf(a.z, v.z, z2.z); z2.w = fmaf(a.z, v.w, z2.w);
        z3.x = fmaf(a.w, v.x, z3.x); z3.y = fmaf(a.w, v.y, z3.y);
        z3.z = fmaf(a.w, v.z, z3.z); z3.w = fmaf(a.w, v.w, z3.w);
    }

    // ---- corrections + dr + stores ----
    float4 dr4;
    {
        float drp[4];
        float4 zz[4] = { z0, z1, z2, z3 };
        #pragma unroll
        for (int j = 0; j < 4; ++j) {
            const int idxj = s_idxv[j];
            const float aj = s_aidx[j];
            float4 sl = mem4[(idxj << 8) + t];
            float4 xj = s_x[j][t];
            float4 d = make_float4(xj.x - sl.x, xj.y - sl.y, xj.z - sl.z, xj.w - sl.w);
            zz[j].x = fmaf(aj, d.x, zz[j].x);
            zz[j].y = fmaf(aj, d.y, zz[j].y);
            zz[j].z = fmaf(aj, d.z, zz[j].z);
            zz[j].w = fmaf(aj, d.w, zz[j].w);
            float ex = zz[j].x - xj.x, ey = zz[j].y - xj.y;
            float ez = zz[j].z - xj.z, ew = zz[j].w - xj.w;
            drp[j] = ex*ex + ey*ey + ez*ez + ew*ew;
            ((float4*)out)[(size_t)(b0 + j) * C4 + t] = zz[j];
        }
        dr4 = make_float4(drp[0], drp[1], drp[2], drp[3]);
        #pragma unroll
        for (int off = 32; off; off >>= 1) {
            dr4.x += __shfl_xor(dr4.x, off, 64);
            dr4.y += __shfl_xor(dr4.y, off, 64);
            dr4.z += __shfl_xor(dr4.z, off, 64);
            dr4.w += __shfl_xor(dr4.w, off, 64);
        }
    }
    if (lane == 0) s_red4[wv] = dr4;
    __syncthreads();                                   // barrier 4
    if (t == 0) {
        float4 s = s_red4[0];
        s.x += s_red4[1].x + s_red4[2].x + s_red4[3].x;
        s.y += s_red4[1].y + s_red4[2].y + s_red4[3].y;
        s.z += s_red4[1].z + s_red4[2].z + s_red4[3].z;
        s.w += s_red4[1].w + s_red4[2].w + s_red4[3].w;
        out[KL_OFF + b0 + 0] = 0.5f * (s_dw[0] + s.x);
        out[KL_OFF + b0 + 1] = 0.5f * (s_dw[1] + s.y);
        out[KL_OFF + b0 + 2] = 0.5f * (s_dw[2] + s.z);
        out[KL_OFF + b0 + 3] = 0.5f * (s_dw[3] + s.w);
    }
}

// Kernel B: blend-row fixup. 256 blocks x 256 thr, ~1 MB of writes.
__global__ __launch_bounds__(256) void tm_fix(const float* __restrict__ x,
                                              const float* __restrict__ mem,
                                              const int* __restrict__ idx_ws,
                                              float* __restrict__ out_um) {
    const int b = blockIdx.x;
    const int t = threadIdx.x;
    const int idx = idx_ws[b];
    float4 sl = ((const float4*)mem)[(idx << 8) + t];
    float4 xv = ((const float4*)(x + (size_t)b * C_DIM))[t];
    ((float4*)out_um)[((size_t)b << 16) + (idx << 8) + t] = blend9(sl, xv);
}

extern "C" void kernel_launch(void* const* d_in, const int* in_sizes, int n_in,
                              void* d_out, int out_size, void* d_ws, size_t ws_size,
                              hipStream_t stream) {
    const float* x   = (const float*)d_in[0];   // input_encoded [B, C]
    const float* mem = (const float*)d_in[1];   // memory_mean  [M, C]
    float* out = (float*)d_out;
    int* idx_ws = (int*)d_ws;

    tm_main<<<dim3(NPRE + NSTRM), dim3(256), 0, stream>>>(x, mem, out, idx_ws);
    tm_fix<<<dim3(B_DIM), dim3(256), 0, stream>>>(x, mem, idx_ws, out + UM_OFF);
}

// Round 15
// 67.188 us; speedup vs baseline: 1.2529x; 1.2529x over previous
//
#include <hip/hip_runtime.h>
#include <math.h>

#define B_DIM 256
#define M_DIM 256
#define C_DIM 1024
#define C4    256            // C/4 float4 per row
#define UM_OFF (B_DIM * C_DIM)                       // 262144 floats
#define KL_OFF (UM_OFF + B_DIM * M_DIM * C_DIM)      // 67371008 floats
#define SCALE  0.03125f      // 1/sqrt(1024)

__device__ __forceinline__ float dot4(float4 a, float4 b) {
    return a.x*b.x + a.y*b.y + a.z*b.z + a.w*b.w;
}
__device__ __forceinline__ float wsum(float v) {
    #pragma unroll
    for (int off = 32; off; off >>= 1) v += __shfl_xor(v, off, 64);
    return v;
}
__device__ __forceinline__ float wmax(float v) {
    #pragma unroll
    for (int off = 32; off; off >>= 1) v = fmaxf(v, __shfl_xor(v, off, 64));
    return v;
}
__device__ __forceinline__ float4 blend9(float4 v, float4 xr) {
    return make_float4(0.9f*v.x + 0.1f*xr.x, 0.9f*v.y + 0.1f*xr.y,
                       0.9f*v.z + 0.1f*xr.z, 0.9f*v.w + 0.1f*xr.w);
}

// ---------------- K1: prefix + z + kl. One block per batch, 1024 thr (R12 verbatim).
__global__ __launch_bounds__(1024) void tm_pre(const float* __restrict__ x,
                                               const float* __restrict__ mem,
                                               float* __restrict__ out,
                                               int* __restrict__ idx_ws) {
    const int b = blockIdx.x;
    const int t = threadIdx.x;
    const int lane = t & 63;
    const int wv = t >> 6;      // 0..15
    const int tc = t & 255;     // column float4 id
    const int q  = t >> 8;      // 0..3 (m-quarter)

    __shared__ float4 s_x[C4];        // 4 KB
    __shared__ float4 s_zp[3][C4];    // 12 KB
    __shared__ float  s_sims[M_DIM];  // 1 KB
    __shared__ float  s_w[4];

    const float4* mem4 = (const float4*)mem;

    // ---- P1: stage x ----
    float4 xv = make_float4(0.f, 0.f, 0.f, 0.f);
    if (q == 0) {
        xv = ((const float4*)(x + (size_t)b * C_DIM))[tc];
        s_x[tc] = xv;
    }
    __syncthreads();                                   // barrier 1

    // ---- P2: sims (wave wv owns m = wv*16 .. +15) ----
    {
        const float4 xr0 = s_x[lane];
        const float4 xr1 = s_x[lane + 64];
        const float4 xr2 = s_x[lane + 128];
        const float4 xr3 = s_x[lane + 192];
        #pragma unroll 4
        for (int i = 0; i < 16; ++i) {
            const int m = (wv << 4) | i;
            const float4* mr = mem4 + (m << 8);
            float acc = dot4(mr[lane],     xr0) + dot4(mr[lane+64],  xr1)
                      + dot4(mr[lane+128], xr2) + dot4(mr[lane+192], xr3);
            acc = wsum(acc);
            if (lane == 0) s_sims[m] = acc;
        }
    }
    __syncthreads();                                   // barrier 2

    // ---- P3: per-wave redundant softmax (zero barriers) ----
    const float v0 = s_sims[lane];
    const float v1 = s_sims[lane + 64];
    const float v2 = s_sims[lane + 128];
    const float v3 = s_sims[lane + 192];
    const float4 xa = s_x[lane], xb = s_x[lane + 64];
    const float4 xc = s_x[lane + 128], xd = s_x[lane + 192];
    const float n2 = wsum(dot4(xa,xa) + dot4(xb,xb) + dot4(xc,xc) + dot4(xd,xd));

    // argmax, first-max tie-break
    float av = v0; int am = lane;
    if (v1 > av) { av = v1; am = lane + 64; }
    if (v2 > av) { av = v2; am = lane + 128; }
    if (v3 > av) { av = v3; am = lane + 192; }
    #pragma unroll
    for (int off = 32; off; off >>= 1) {
        float ov = __shfl_xor(av, off, 64);
        int   oi = __shfl_xor(am, off, 64);
        if (ov > av || (ov == av && oi < am)) { av = ov; am = oi; }
    }
    const int idx = am;
    if (t == 0) idx_ws[b] = idx;       // visible to tm_stream at kernel boundary
    const float fused = 0.9f * av + 0.1f * n2;

    float s0 = ((lane      ) == idx ? fused : v0) * SCALE;
    float s1 = ((lane +  64) == idx ? fused : v1) * SCALE;
    float s2 = ((lane + 128) == idx ? fused : v2) * SCALE;
    float s3 = ((lane + 192) == idx ? fused : v3) * SCALE;
    const float mx = wmax(fmaxf(fmaxf(s0, s1), fmaxf(s2, s3)));
    const float e0 = expf(s0 - mx), e1 = expf(s1 - mx);
    const float e2 = expf(s2 - mx), e3 = expf(s3 - mx);
    const float inv = 1.0f / wsum(e0 + e1 + e2 + e3);
    const float a0 = e0 * inv, a1 = e1 * inv, a2 = e2 * inv, a3 = e3 * inv;

    float aidx;
    if      (idx <  64) aidx = __shfl(a0, idx,       64);
    else if (idx < 128) aidx = __shfl(a1, idx - 64,  64);
    else if (idx < 192) aidx = __shfl(a2, idx - 128, 64);
    else                aidx = __shfl(a3, idx - 192, 64);
    aidx *= 0.1f;

    // dw = ||x - mem[idx]||^2 (wave 0 only)
    float dw = 0.f;
    if (wv == 0) {
        const float4* ir = mem4 + (idx << 8);
        float4 q0 = ir[lane], q1 = ir[lane+64], q2 = ir[lane+128], q3 = ir[lane+192];
        float p = 0.f; float4 dq;
        dq = make_float4(xa.x-q0.x, xa.y-q0.y, xa.z-q0.z, xa.w-q0.w); p += dot4(dq,dq);
        dq = make_float4(xb.x-q1.x, xb.y-q1.y, xb.z-q1.z, xb.w-q1.w); p += dot4(dq,dq);
        dq = make_float4(xc.x-q2.x, xc.y-q2.y, xc.z-q2.z, xc.w-q2.w); p += dot4(dq,dq);
        dq = make_float4(xd.x-q3.x, xd.y-q3.y, xd.z-q3.z, xd.w-q3.w); p += dot4(dq,dq);
        dw = wsum(p);
    }

    // ---- P4: z partial (quarter q covers m = q*64 .. +63); attn via shfl ----
    float4 z = make_float4(0.f, 0.f, 0.f, 0.f);
    {
        const float4* zsrc = mem4 + ((q << 6) << 8) + tc;
        auto zrun = [&](float areg) {
            #pragma unroll 4
            for (int i = 0; i < 64; ++i) {
                const float a = __shfl(areg, i, 64);
                float4 v = zsrc[i << 8];
                z.x = fmaf(a, v.x, z.x);
                z.y = fmaf(a, v.y, z.y);
                z.z = fmaf(a, v.z, z.z);
                z.w = fmaf(a, v.w, z.w);
            }
        };
        if      (q == 0) zrun(a0);
        else if (q == 1) zrun(a1);
        else if (q == 2) zrun(a2);
        else             zrun(a3);
    }
    if (q) s_zp[q - 1][tc] = z;
    __syncthreads();                                   // barrier 3
    float drp = 0.f;
    if (q == 0) {
        float4 z1 = s_zp[0][tc], z2 = s_zp[1][tc], z3 = s_zp[2][tc];
        z.x += z1.x + z2.x + z3.x;
        z.y += z1.y + z2.y + z3.y;
        z.z += z1.z + z2.z + z3.z;
        z.w += z1.w + z2.w + z3.w;
        float4 sl = mem4[(idx << 8) + tc];
        float4 d = make_float4(xv.x - sl.x, xv.y - sl.y, xv.z - sl.z, xv.w - sl.w);
        z.x = fmaf(aidx, d.x, z.x);
        z.y = fmaf(aidx, d.y, z.y);
        z.z = fmaf(aidx, d.z, z.z);
        z.w = fmaf(aidx, d.w, z.w);
        float ex = z.x - xv.x, ey = z.y - xv.y, ez = z.z - xv.z, ew = z.w - xv.w;
        drp = ex*ex + ey*ey + ez*ez + ew*ew;
        ((float4*)out)[(size_t)b * C4 + tc] = z;
    }
    {
        float s = wsum(drp);
        if (q == 0 && lane == 0) s_w[wv] = s;          // wv 0..3
    }
    __syncthreads();                                   // barrier 4
    if (t == 0) out[KL_OFF + b] = 0.5f * (dw + s_w[0] + s_w[1] + s_w[2] + s_w[3]);
}

// ---------------- K2: fanout stream. 4096 blocks x 256 thr.
// Block j: 8 rows read ONCE, written to a PAIR of batches (halves L2 read
// transactions vs R12). All loads before stores; regular stores; inline blend.
__global__ __launch_bounds__(256) void tm_stream(const float* __restrict__ x,
                                                 const float* __restrict__ mem,
                                                 const int* __restrict__ idx_ws,
                                                 float* __restrict__ out_um) {
    const int j = blockIdx.x;       // 0..4095
    const int p  = j >> 5;          // b-pair 0..127
    const int b0 = p << 1;
    const int m0 = (j & 31) << 3;   // 0,8,...,248
    const int t = threadIdx.x;      // column float4 id

    const float4* src = (const float4*)mem + (m0 << 8) + t;
    float4 r0 = src[0 << 8];
    float4 r1 = src[1 << 8];
    float4 r2 = src[2 << 8];
    float4 r3 = src[3 << 8];
    float4 r4 = src[4 << 8];
    float4 r5 = src[5 << 8];
    float4 r6 = src[6 << 8];
    float4 r7 = src[7 << 8];

    const int liA = idx_ws[b0]     - m0;   // blend row for batch b0 if in [0,8)
    const int liB = idx_ws[b0 + 1] - m0;   // blend row for batch b0+1
    float4 xvA = make_float4(0.f, 0.f, 0.f, 0.f);
    float4 xvB = make_float4(0.f, 0.f, 0.f, 0.f);
    if (liA >= 0 && liA < 8) xvA = ((const float4*)(x + (size_t)b0 * C_DIM))[t];
    if (liB >= 0 && liB < 8) xvB = ((const float4*)(x + (size_t)(b0+1) * C_DIM))[t];

    float4* dstA = (float4*)out_um + ((size_t)b0 << 16) + (m0 << 8) + t;
    dstA[0 << 8] = (liA == 0) ? blend9(r0, xvA) : r0;
    dstA[1 << 8] = (liA == 1) ? blend9(r1, xvA) : r1;
    dstA[2 << 8] = (liA == 2) ? blend9(r2, xvA) : r2;
    dstA[3 << 8] = (liA == 3) ? blend9(r3, xvA) : r3;
    dstA[4 << 8] = (liA == 4) ? blend9(r4, xvA) : r4;
    dstA[5 << 8] = (liA == 5) ? blend9(r5, xvA) : r5;
    dstA[6 << 8] = (liA == 6) ? blend9(r6, xvA) : r6;
    dstA[7 << 8] = (liA == 7) ? blend9(r7, xvA) : r7;

    float4* dstB = dstA + ((size_t)1 << 16);
    dstB[0 << 8] = (liB == 0) ? blend9(r0, xvB) : r0;
    dstB[1 << 8] = (liB == 1) ? blend9(r1, xvB) : r1;
    dstB[2 << 8] = (liB == 2) ? blend9(r2, xvB) : r2;
    dstB[3 << 8] = (liB == 3) ? blend9(r3, xvB) : r3;
    dstB[4 << 8] = (liB == 4) ? blend9(r4, xvB) : r4;
    dstB[5 << 8] = (liB == 5) ? blend9(r5, xvB) : r5;
    dstB[6 << 8] = (liB == 6) ? blend9(r6, xvB) : r6;
    dstB[7 << 8] = (liB == 7) ? blend9(r7, xvB) : r7;
}

extern "C" void kernel_launch(void* const* d_in, const int* in_sizes, int n_in,
                              void* d_out, int out_size, void* d_ws, size_t ws_size,
                              hipStream_t stream) {
    const float* x   = (const float*)d_in[0];   // input_encoded [B, C]
    const float* mem = (const float*)d_in[1];   // memory_mean  [M, C]
    float* out = (float*)d_out;
    int* idx_ws = (int*)d_ws;

    tm_pre<<<dim3(B_DIM), dim3(1024), 0, stream>>>(x, mem, out, idx_ws);
    tm_stream<<<dim3(4096), dim3(256), 0, stream>>>(x, mem, idx_ws, out + UM_OFF);
}

// Round 16
// 60.140 us; speedup vs baseline: 1.3998x; 1.1172x over previous
//
#include <hip/hip_runtime.h>
#include <math.h>

#define B_DIM 256
#define M_DIM 256
#define C_DIM 1024
#define C4    256            // C/4 float4 per row
#define UM_OFF (B_DIM * C_DIM)                       // 262144 floats
#define KL_OFF (UM_OFF + B_DIM * M_DIM * C_DIM)      // 67371008 floats
#define SCALE  0.03125f      // 1/sqrt(1024)

__device__ __forceinline__ float dot4(float4 a, float4 b) {
    return a.x*b.x + a.y*b.y + a.z*b.z + a.w*b.w;
}
__device__ __forceinline__ float wsum(float v) {
    #pragma unroll
    for (int off = 32; off; off >>= 1) v += __shfl_xor(v, off, 64);
    return v;
}
__device__ __forceinline__ float wmax(float v) {
    #pragma unroll
    for (int off = 32; off; off >>= 1) v = fmaxf(v, __shfl_xor(v, off, 64));
    return v;
}
__device__ __forceinline__ float4 blend9(float4 v, float4 xr) {
    return make_float4(0.9f*v.x + 0.1f*xr.x, 0.9f*v.y + 0.1f*xr.y,
                       0.9f*v.z + 0.1f*xr.z, 0.9f*v.w + 0.1f*xr.w);
}

// ---------------- K1: stream + free-rider sims. 8192 blocks x 256 thr.
// Block j: batch b=j>>5, rows m0..m0+7. Loads 8 rows + x-chunk, computes the
// 8 sims dots from the SAME registers (all reduction before any store), stashes
// sims into out's z-row region, then burst-stores the 8 raw rows.
__global__ __launch_bounds__(256) void tm_stream(const float* __restrict__ x,
                                                 const float* __restrict__ mem,
                                                 float* __restrict__ out) {
    const int j = blockIdx.x;       // 0..8191
    const int b  = j >> 5;
    const int m0 = (j & 31) << 3;   // 0,8,...,248
    const int t = threadIdx.x;      // column float4 id
    const int lane = t & 63;
    const int wv = t >> 6;          // 0..3

    __shared__ float s_p[8][4];     // [row][wave]

    const float4* src = (const float4*)mem + (m0 << 8) + t;
    float4 r0 = src[0 << 8];
    float4 r1 = src[1 << 8];
    float4 r2 = src[2 << 8];
    float4 r3 = src[3 << 8];
    float4 r4 = src[4 << 8];
    float4 r5 = src[5 << 8];
    float4 r6 = src[6 << 8];
    float4 r7 = src[7 << 8];
    const float4 xv = ((const float4*)(x + (size_t)b * C_DIM))[t];

    // sims partials from already-staged registers
    float p0 = dot4(r0, xv), p1 = dot4(r1, xv), p2 = dot4(r2, xv), p3 = dot4(r3, xv);
    float p4 = dot4(r4, xv), p5 = dot4(r5, xv), p6 = dot4(r6, xv), p7 = dot4(r7, xv);
    p0 = wsum(p0); p1 = wsum(p1); p2 = wsum(p2); p3 = wsum(p3);
    p4 = wsum(p4); p5 = wsum(p5); p6 = wsum(p6); p7 = wsum(p7);
    if (lane == 0) {
        s_p[0][wv] = p0; s_p[1][wv] = p1; s_p[2][wv] = p2; s_p[3][wv] = p3;
        s_p[4][wv] = p4; s_p[5][wv] = p5; s_p[6][wv] = p6; s_p[7][wv] = p7;
    }
    __syncthreads();
    if (t < 8)
        out[(size_t)b * C_DIM + m0 + t] = s_p[t][0] + s_p[t][1] + s_p[t][2] + s_p[t][3];

    // pure store burst (raw rows; blend row rewritten by K2)
    float4* dst = (float4*)(out + UM_OFF) + ((size_t)b << 16) + (m0 << 8) + t;
    dst[0 << 8] = r0;
    dst[1 << 8] = r1;
    dst[2 << 8] = r2;
    dst[3 << 8] = r3;
    dst[4 << 8] = r4;
    dst[5 << 8] = r5;
    dst[6 << 8] = r6;
    dst[7 << 8] = r7;
}

// ---------------- K2: softmax + z + kl + blend-row. 256 blocks x 1024 thr.
// R12's tm_pre minus the sims pass (sims read from out's z-row stash, then
// overwritten by z after barrier 3).
__global__ __launch_bounds__(1024) void tm_post(const float* __restrict__ x,
                                                const float* __restrict__ mem,
                                                float* __restrict__ out) {
    const int b = blockIdx.x;
    const int t = threadIdx.x;
    const int lane = t & 63;
    const int wv = t >> 6;      // 0..15
    const int tc = t & 255;     // column float4 id
    const int q  = t >> 8;      // 0..3 (m-quarter)

    __shared__ float4 s_x[C4];        // 4 KB
    __shared__ float4 s_zp[3][C4];    // 12 KB
    __shared__ float  s_w[4];

    const float4* mem4 = (const float4*)mem;

    // ---- P1: stage x ----
    float4 xv = make_float4(0.f, 0.f, 0.f, 0.f);
    if (q == 0) {
        xv = ((const float4*)(x + (size_t)b * C_DIM))[tc];
        s_x[tc] = xv;
    }
    __syncthreads();                                   // barrier 1

    // ---- P3': per-wave redundant softmax; sims from global stash ----
    const float* simsrow = out + (size_t)b * C_DIM;
    const float v0 = simsrow[lane];
    const float v1 = simsrow[lane + 64];
    const float v2 = simsrow[lane + 128];
    const float v3 = simsrow[lane + 192];
    const float4 xa = s_x[lane], xb = s_x[lane + 64];
    const float4 xc = s_x[lane + 128], xd = s_x[lane + 192];
    const float n2 = wsum(dot4(xa,xa) + dot4(xb,xb) + dot4(xc,xc) + dot4(xd,xd));

    // argmax, first-max tie-break
    float av = v0; int am = lane;
    if (v1 > av) { av = v1; am = lane + 64; }
    if (v2 > av) { av = v2; am = lane + 128; }
    if (v3 > av) { av = v3; am = lane + 192; }
    #pragma unroll
    for (int off = 32; off; off >>= 1) {
        float ov = __shfl_xor(av, off, 64);
        int   oi = __shfl_xor(am, off, 64);
        if (ov > av || (ov == av && oi < am)) { av = ov; am = oi; }
    }
    const int idx = am;
    const float fused = 0.9f * av + 0.1f * n2;

    float s0 = ((lane      ) == idx ? fused : v0) * SCALE;
    float s1 = ((lane +  64) == idx ? fused : v1) * SCALE;
    float s2 = ((lane + 128) == idx ? fused : v2) * SCALE;
    float s3 = ((lane + 192) == idx ? fused : v3) * SCALE;
    const float mx = wmax(fmaxf(fmaxf(s0, s1), fmaxf(s2, s3)));
    const float e0 = expf(s0 - mx), e1 = expf(s1 - mx);
    const float e2 = expf(s2 - mx), e3 = expf(s3 - mx);
    const float inv = 1.0f / wsum(e0 + e1 + e2 + e3);
    const float a0 = e0 * inv, a1 = e1 * inv, a2 = e2 * inv, a3 = e3 * inv;

    float aidx;
    if      (idx <  64) aidx = __shfl(a0, idx,       64);
    else if (idx < 128) aidx = __shfl(a1, idx - 64,  64);
    else if (idx < 192) aidx = __shfl(a2, idx - 128, 64);
    else                aidx = __shfl(a3, idx - 192, 64);
    aidx *= 0.1f;

    // dw = ||x - mem[idx]||^2 (wave 0 only)
    float dw = 0.f;
    if (wv == 0) {
        const float4* ir = mem4 + (idx << 8);
        float4 q0 = ir[lane], q1 = ir[lane+64], q2 = ir[lane+128], q3 = ir[lane+192];
        float p = 0.f; float4 dq;
        dq = make_float4(xa.x-q0.x, xa.y-q0.y, xa.z-q0.z, xa.w-q0.w); p += dot4(dq,dq);
        dq = make_float4(xb.x-q1.x, xb.y-q1.y, xb.z-q1.z, xb.w-q1.w); p += dot4(dq,dq);
        dq = make_float4(xc.x-q2.x, xc.y-q2.y, xc.z-q2.z, xc.w-q2.w); p += dot4(dq,dq);
        dq = make_float4(xd.x-q3.x, xd.y-q3.y, xd.z-q3.z, xd.w-q3.w); p += dot4(dq,dq);
        dw = wsum(p);
    }

    // ---- P4: z partial (quarter q covers m = q*64 .. +63); attn via shfl ----
    float4 z = make_float4(0.f, 0.f, 0.f, 0.f);
    {
        const float4* zsrc = mem4 + ((q << 6) << 8) + tc;
        auto zrun = [&](float areg) {
            #pragma unroll 4
            for (int i = 0; i < 64; ++i) {
                const float a = __shfl(areg, i, 64);
                float4 v = zsrc[i << 8];
                z.x = fmaf(a, v.x, z.x);
                z.y = fmaf(a, v.y, z.y);
                z.z = fmaf(a, v.z, z.z);
                z.w = fmaf(a, v.w, z.w);
            }
        };
        if      (q == 0) zrun(a0);
        else if (q == 1) zrun(a1);
        else if (q == 2) zrun(a2);
        else             zrun(a3);
    }
    if (q) s_zp[q - 1][tc] = z;
    __syncthreads();                                   // barrier 3 (all sims reads done)
    float drp = 0.f;
    if (q == 0) {
        float4 z1 = s_zp[0][tc], z2 = s_zp[1][tc], z3 = s_zp[2][tc];
        z.x += z1.x + z2.x + z3.x;
        z.y += z1.y + z2.y + z3.y;
        z.z += z1.z + z2.z + z3.z;
        z.w += z1.w + z2.w + z3.w;
        float4 sl = mem4[(idx << 8) + tc];
        float4 d = make_float4(xv.x - sl.x, xv.y - sl.y, xv.z - sl.z, xv.w - sl.w);
        z.x = fmaf(aidx, d.x, z.x);
        z.y = fmaf(aidx, d.y, z.y);
        z.z = fmaf(aidx, d.z, z.z);
        z.w = fmaf(aidx, d.w, z.w);
        float ex = z.x - xv.x, ey = z.y - xv.y, ez = z.z - xv.z, ew = z.w - xv.w;
        drp = ex*ex + ey*ey + ez*ez + ew*ew;
        ((float4*)out)[(size_t)b * C4 + tc] = z;       // overwrites sims stash
        // blend-row rewrite (K1 wrote it raw; kernel boundary orders us after)
        ((float4*)(out + UM_OFF))[((size_t)b << 16) + (idx << 8) + tc] = blend9(sl, xv);
    }
    {
        float s = wsum(drp);
        if (q == 0 && lane == 0) s_w[wv] = s;          // wv 0..3
    }
    __syncthreads();                                   // barrier 4
    if (t == 0) out[KL_OFF + b] = 0.5f * (dw + s_w[0] + s_w[1] + s_w[2] + s_w[3]);
}

extern "C" void kernel_launch(void* const* d_in, const int* in_sizes, int n_in,
                              void* d_out, int out_size, void* d_ws, size_t ws_size,
                              hipStream_t stream) {
    const float* x   = (const float*)d_in[0];   // input_encoded [B, C]
    const float* mem = (const float*)d_in[1];   // memory_mean  [M, C]
    float* out = (float*)d_out;

    tm_stream<<<dim3(8192), dim3(256), 0, stream>>>(x, mem, out);
    tm_post<<<dim3(B_DIM), dim3(1024), 0, stream>>>(x, mem, out);
}